// Round 14
// baseline (14.515 us; speedup 1.0000x reference)
//
#include <hip/hip_runtime.h>
#include <math.h>

#define BATCH 128
#define NPRE  1024
#define NPOST 256
#define NJB   128    // neurons per block (2 per lane, float2 columns)
#define NW    16     // waves per block
#define KPW   16     // k's per wave per chunk
#define CLEN  256    // chunk length = NW*KPW
#define NCHK  4      // NPRE / CLEN

__device__ __forceinline__ float lambertw0_f(float z) {
    // Principal branch for z in [-1/e, 0). Same clip+init as reference; Halley
    // converges cubically, 5 iters is fp32-converged (reference's 12 are no-ops).
    const float INV_E = 0.36787944117144233f;
    float zc = fminf(fmaxf(z, -INV_E + 1e-8f), -1e-30f);
    float w;
    if (zc < -0.2f) {
        w = -1.0f + sqrtf(2.0f * (1.0f + 2.718281828459045f * zc));
    } else {
        w = zc * (1.0f - zc);
    }
#pragma unroll
    for (int it = 0; it < 5; ++it) {
        float ew  = expf(w);
        float f   = w * ew - zc;
        float wp1 = w + 1.0f;
        w = w - f / (ew * wp1 - (w + 2.0f) * f / (2.0f * wp1));
    }
    return w;
}

__global__ __launch_bounds__(1024, 4)
void ttfs_kernel(const float* __restrict__ spikes,   // (BATCH, NPRE)
                 const float* __restrict__ Wt,       // (NPRE, NPOST)
                 float* __restrict__ out)            // (BATCH, NPOST)
{
    // ---- histogram-sort scratch ----
    __shared__ int    cnt[1024];
    __shared__ int    bstart[1025];
    __shared__ int    wsum[NW];
    __shared__ unsigned long long tmp64[NPRE];
    // ---- split tables ----
    __shared__ float2 tse[NPRE + 1];             // (s, e^s) sorted, +inf pad
    __shared__ float2 tez[NPRE + 1];             // (e^s, s*e^s) sorted
    __shared__ int    sidx[NPRE + 4];            // sorted original indices
    __shared__ float  pA[NW][NJB + 2], pB[NW][NJB + 2];
    __shared__ int    flags[2];
    __shared__ int    rbaseK[NJB];               // per-neuron firing-group start
    __shared__ float  rpreA[NJB], rpreB[NJB];    // per-neuron prefix before group

    const int tid  = threadIdx.x;
    const int lane = tid & 63;
    const int wid  = tid >> 6;
    const int b    = (int)blockIdx.x >> 1;
    const int h    = (int)blockIdx.x & 1;

    // ================= histogram rank-sort (stable by (key asc, idx asc)) ==========
    {
        float s = spikes[b * NPRE + tid];
        unsigned long long v =
            (((unsigned long long)__float_as_uint(s)) << 32) | (unsigned)tid;
        int bucket = (int)(s * 1024.0f);
        bucket = bucket < 0 ? 0 : (bucket > 1023 ? 1023 : bucket);

        cnt[tid] = 0;
        __syncthreads();
        int arr = atomicAdd(&cnt[bucket], 1);
        __syncthreads();

        int c0 = cnt[tid];
        int x  = c0;
#pragma unroll
        for (int d = 1; d < 64; d <<= 1) {
            int y = __shfl_up(x, d);
            if (lane >= d) x += y;
        }
        if (lane == 63) wsum[wid] = x;
        __syncthreads();
        // wave-wide shfl scan over the 16 wave totals
        int ws = (lane < NW) ? wsum[lane] : 0;
#pragma unroll
        for (int d = 1; d < NW; d <<= 1) {
            int y = __shfl_up(ws, d);
            if (lane >= d) ws += y;
        }
        int base = (wid == 0) ? 0 : __shfl(ws, wid - 1);
        bstart[tid] = base + x - c0;
        if (tid == 0) bstart[1024] = NPRE;
        __syncthreads();

        int slot = bstart[bucket] + arr;
        tmp64[slot] = v;
        __syncthreads();

        int st = bstart[bucket], en = bstart[bucket + 1];
        int rk = 0;
        for (int q = st; q < en; ++q) rk += (tmp64[q] < v);
        int fin = st + rk;

        float e = expf(s);
        tse[fin]  = make_float2(s, e);
        tez[fin]  = make_float2(e, s * e);
        sidx[fin] = tid;
    }
    if (tid == 0) {
        tse[NPRE]  = make_float2(INFINITY, INFINITY);
        tez[NPRE]  = make_float2(INFINITY, 0.0f);
        sidx[NPRE] = 0; sidx[NPRE + 1] = 0; sidx[NPRE + 2] = 0; sidx[NPRE + 3] = 0;
    }
    __syncthreads();

    // ================= sequential-chunk scan with block early-exit ================
    const int j0 = h * NJB;
    const int4* __restrict__ sidx4 = (const int4*)sidx;
    const int kbase = wid * KPW;                           // wave's k-slice in chunk

    // reduce-wave state (wave w<2 owns neuron n = 2*lane + w)
    float offA = 0.0f, offB = 0.0f;
    float preA = 0.0f, preB = 0.0f;
    int   baseK = -1;
    bool  doneJ = false;

    // float2 gather: lane covers neurons (j0+2*lane, j0+2*lane+1) in one 8B load
#define LW2(idx) (*(const float2*)(Wt + (idx) * NPOST + j0 + 2 * lane))
#define LOADW2(kstart, dst)                                                   \
    {                                                                         \
        int4 Ia = sidx4[((kstart) >> 2) + 0];                                 \
        int4 Ib = sidx4[((kstart) >> 2) + 1];                                 \
        int4 Ic = sidx4[((kstart) >> 2) + 2];                                 \
        int4 Id = sidx4[((kstart) >> 2) + 3];                                 \
        dst[0]  = LW2(Ia.x); dst[1]  = LW2(Ia.y);                             \
        dst[2]  = LW2(Ia.z); dst[3]  = LW2(Ia.w);                             \
        dst[4]  = LW2(Ib.x); dst[5]  = LW2(Ib.y);                             \
        dst[6]  = LW2(Ib.z); dst[7]  = LW2(Ib.w);                             \
        dst[8]  = LW2(Ic.x); dst[9]  = LW2(Ic.y);                             \
        dst[10] = LW2(Ic.z); dst[11] = LW2(Ic.w);                             \
        dst[12] = LW2(Id.x); dst[13] = LW2(Id.y);                             \
        dst[14] = LW2(Id.z); dst[15] = LW2(Id.w);                             \
    }

    float2 wv[KPW];
    LOADW2(kbase, wv);

    for (int ch = 0; ch < NCHK; ++ch) {
        const int kk0 = ch * CLEN + kbase;
        // wave-local partials over its 16 k's (tez reads: wave-uniform broadcasts)
        float a0 = 0.0f, b0 = 0.0f, a1 = 0.0f, b1 = 0.0f;
#pragma unroll
        for (int i = 0; i < KPW; ++i) {
            float2 t = tez[kk0 + i];
            a0 = fmaf(wv[i].x, t.x, a0);
            b0 = fmaf(wv[i].x, t.y, b0);
            a1 = fmaf(wv[i].y, t.x, a1);
            b1 = fmaf(wv[i].y, t.y, b1);
        }
        pA[wid][2 * lane]     = a0; pB[wid][2 * lane]     = b0;
        pA[wid][2 * lane + 1] = a1; pB[wid][2 * lane + 1] = b1;
        __syncthreads();

        if (wid < 2) {
            const int n = 2 * lane + wid;
            // sub-gated prefix over the 16 wave-partials: gate every KPW k's.
#pragma unroll
            for (int w = 0; w < NW; ++w) {
                float nA = offA + pA[w][n];
                float nB = offB + pB[w][n];
                if (!doneJ) {
                    float2 tn = tse[ch * CLEN + (w + 1) * KPW];   // last: pad ok
                    float gate = fmaf(nA, tn.x, -nB);
                    if (gate >= tn.y) {
                        baseK = ch * CLEN + w * KPW;
                        preA = offA; preB = offB;
                        doneJ = true;
                    }
                }
                offA = nA; offB = nB;
            }
            bool all = __all(doneJ);
            if (lane == 0) flags[wid] = all ? 1 : 0;
        }
        __syncthreads();
        if (flags[0] & flags[1]) break;        // uniform across block (typ. ch=0)
        if (ch < NCHK - 1) LOADW2(kk0 + CLEN, wv);
    }

    // publish per-neuron bracket state
    if (wid < 2) {
        const int n = 2 * lane + wid;
        rbaseK[n] = baseK; rpreA[n] = preA; rpreB[n] = preB;
    }
    __syncthreads();

    // ================= parallel resolve: 8 lanes per neuron, all 16 waves ==========
    {
        const int q  = lane >> 3;          // group in wave: 0..7
        const int sl = lane & 7;           // slot in group: 0..7
        const int n  = (wid << 3) + q;     // neuron 0..127
        const float* __restrict__ Wn = Wt + j0 + n;
        const float INV_E = 0.36787944117144233f;
        const int bK = rbaseK[n];

        bool has = false;
        int myfk = 0; float myA = 0.0f, myB = 0.0f;
        if (bK >= 0) {
            const int k0 = bK + 2 * sl;    // this slot's two windows: k0, k0+1
            float w0 = Wn[sidx[k0] * NPOST];
            float w1 = Wn[sidx[k0 + 1] * NPOST];
            float2 e0 = tez[k0], e1 = tez[k0 + 1];
            float la = w0 * e0.x; la = fmaf(w1, e1.x, la);
            float lb = w0 * e0.y; lb = fmaf(w1, e1.y, lb);
            float sa = la, sb = lb;
#pragma unroll
            for (int d = 1; d < 8; d <<= 1) {
                float ua = __shfl_up(sa, d, 8);
                float ub = __shfl_up(sb, d, 8);
                if (sl >= d) { sa += ua; sb += ub; }
            }
            float exA = rpreA[n] + (sa - la);   // prefix excl. this slot's pair
            float exB = rpreB[n] + (sb - lb);
            float A0 = fmaf(w0, e0.x, exA);
            float B0 = fmaf(w0, e0.y, exB);
            float A1 = fmaf(w1, e1.x, A0);
            float B1 = fmaf(w1, e1.y, B0);
            float2 t1 = tse[k0 + 1];
            float2 t2 = tse[k0 + 2];
            bool g0 = fmaf(A0, t1.x, -B0) >= t1.y;   // window k0
            bool g1 = fmaf(A1, t2.x, -B1) >= t2.y;   // window k0+1
            has  = g0 || g1;
            myfk = g0 ? k0 : (k0 + 1);
            myA  = g0 ? A0 : A1;
            myB  = g0 ? B0 : B1;
        }
        unsigned long long bal = __ballot(has);
        if (bK >= 0) {
            unsigned mask8 = (unsigned)((bal >> (q * 8)) & 0xFFull);
            if (mask8 == 0u) {
                // tree/sequential mismatch (ultra-rare): faithful full scan from 0
                if (sl == 0) {
                    float result = INFINITY;
                    float A2 = 0.0f, B2 = 0.0f;
                    for (int k = 0; k < NPRE; ++k) {
                        float w = Wn[sidx[k] * NPOST];
                        float2 ezv = tez[k];
                        A2 = fmaf(w, ezv.x, A2);
                        B2 = fmaf(w, ezv.y, B2);
                        if (A2 <= 0.0f) continue;
                        float r2  = B2 / A2;
                        float ex2 = expf(fminf(fmaxf(r2, -30.0f), 30.0f));
                        float z2  = -ex2 / A2;
                        if (z2 < -INV_E) continue;
                        float t2 = r2 - lambertw0_f(z2);
                        if (t2 < tse[k].x) continue;
                        if (k < NPRE - 1 && t2 > tse[k + 1].x) continue;
                        result = t2;
                        break;
                    }
                    out[b * NPOST + j0 + n] = result;
                }
            } else {
                int f = __ffs((int)mask8) - 1;   // earliest firing slot
                if (sl == f) {
                    float result = INFINITY;
                    float r   = myB / myA;
                    float ezz = expf(fminf(fmaxf(r, -30.0f), 30.0f));
                    float z   = -ezz / myA;
                    bool valid = (myA > 0.0f) && (z >= -INV_E);
                    float t = r - lambertw0_f(z);
                    bool ok = valid && (t >= tse[myfk].x) &&
                              (myfk == NPRE - 1 || t <= tse[myfk + 1].x);
                    if (ok) {
                        result = t;
                    } else {
                        // rare fp-edge fallback: faithful sequential scan from myfk+1
                        float A2 = myA, B2 = myB;
                        for (int k = myfk + 1; k < NPRE; ++k) {
                            float w = Wn[sidx[k] * NPOST];
                            float2 ezv = tez[k];
                            A2 = fmaf(w, ezv.x, A2);
                            B2 = fmaf(w, ezv.y, B2);
                            if (A2 <= 0.0f) continue;
                            float r2  = B2 / A2;
                            float ex2 = expf(fminf(fmaxf(r2, -30.0f), 30.0f));
                            float z2  = -ex2 / A2;
                            if (z2 < -INV_E) continue;
                            float t2 = r2 - lambertw0_f(z2);
                            if (t2 < tse[k].x) continue;
                            if (k < NPRE - 1 && t2 > tse[k + 1].x) continue;
                            result = t2;
                            break;
                        }
                    }
                    out[b * NPOST + j0 + n] = result;
                }
            }
        } else if (sl == 0) {
            out[b * NPOST + j0 + n] = INFINITY;   // neuron never fires
        }
    }
}

extern "C" void kernel_launch(void* const* d_in, const int* in_sizes, int n_in,
                              void* d_out, int out_size, void* d_ws, size_t ws_size,
                              hipStream_t stream) {
    const float* spikes  = (const float*)d_in[0];   // (128, 1024) f32
    const float* weights = (const float*)d_in[1];   // (1024, 256) f32
    float* outp = (float*)d_out;                    // (128, 256) f32
    ttfs_kernel<<<dim3(BATCH * 2), dim3(1024), 0, stream>>>(spikes, weights, outp);
}

// Round 15
// 13.456 us; speedup vs baseline: 1.0787x; 1.0787x over previous
//
#include <hip/hip_runtime.h>
#include <math.h>

#define BATCH 128
#define NPRE  1024
#define NPOST 256
#define NJB   128    // neurons per block (2 per lane, float2 columns)
#define NW    16     // waves per block
#define KPW   16     // k's per wave per chunk
#define CLEN  256    // chunk length = NW*KPW
#define NCHK  4      // NPRE / CLEN

__device__ __forceinline__ float lambertw0_f(float z) {
    // Principal branch for z in [-1/e, 0). Same clip+init as reference; Halley
    // converges cubically, 5 iters is fp32-converged (reference's 12 are no-ops).
    const float INV_E = 0.36787944117144233f;
    float zc = fminf(fmaxf(z, -INV_E + 1e-8f), -1e-30f);
    float w;
    if (zc < -0.2f) {
        w = -1.0f + sqrtf(2.0f * (1.0f + 2.718281828459045f * zc));
    } else {
        w = zc * (1.0f - zc);
    }
#pragma unroll
    for (int it = 0; it < 5; ++it) {
        float ew  = expf(w);
        float f   = w * ew - zc;
        float wp1 = w + 1.0f;
        w = w - f / (ew * wp1 - (w + 2.0f) * f / (2.0f * wp1));
    }
    return w;
}

__global__ __launch_bounds__(1024, 4)
void ttfs_kernel(const float* __restrict__ spikes,   // (BATCH, NPRE)
                 const float* __restrict__ Wt,       // (NPRE, NPOST)
                 float* __restrict__ out)            // (BATCH, NPOST)
{
    // ---- histogram-sort scratch ----
    __shared__ int    cnt[1024];
    __shared__ int    bstart[1025];
    __shared__ int    wsum[NW];
    __shared__ unsigned long long tmp64[NPRE];
    // ---- split tables ----
    __shared__ float2 tse[NPRE + 1];             // (s, e^s) sorted, +inf pad
    __shared__ float2 tez[NPRE + 1];             // (e^s, s*e^s) sorted
    __shared__ int    sidx[NPRE + 4];            // sorted original indices
    __shared__ float  pA[NW][NJB + 2], pB[NW][NJB + 2];
    __shared__ int    flags[2];

    const int tid  = threadIdx.x;
    const int lane = tid & 63;
    const int wid  = tid >> 6;
    const int b    = (int)blockIdx.x >> 1;
    const int h    = (int)blockIdx.x & 1;

    // ================= histogram rank-sort (stable by (key asc, idx asc)) ==========
    {
        float s = spikes[b * NPRE + tid];
        unsigned long long v =
            (((unsigned long long)__float_as_uint(s)) << 32) | (unsigned)tid;
        int bucket = (int)(s * 1024.0f);
        bucket = bucket < 0 ? 0 : (bucket > 1023 ? 1023 : bucket);

        cnt[tid] = 0;
        __syncthreads();
        int arr = atomicAdd(&cnt[bucket], 1);
        __syncthreads();

        int c0 = cnt[tid];
        int x  = c0;
#pragma unroll
        for (int d = 1; d < 64; d <<= 1) {
            int y = __shfl_up(x, d);
            if (lane >= d) x += y;
        }
        if (lane == 63) wsum[wid] = x;
        __syncthreads();
        // wave-wide shfl scan over the 16 wave totals
        int ws = (lane < NW) ? wsum[lane] : 0;
#pragma unroll
        for (int d = 1; d < NW; d <<= 1) {
            int y = __shfl_up(ws, d);
            if (lane >= d) ws += y;
        }
        int base = (wid == 0) ? 0 : __shfl(ws, wid - 1);
        bstart[tid] = base + x - c0;
        if (tid == 0) bstart[1024] = NPRE;
        __syncthreads();

        int slot = bstart[bucket] + arr;
        tmp64[slot] = v;
        __syncthreads();

        int st = bstart[bucket], en = bstart[bucket + 1];
        int rk = 0;
        for (int q = st; q < en; ++q) rk += (tmp64[q] < v);
        int fin = st + rk;

        float e = expf(s);
        tse[fin]  = make_float2(s, e);
        tez[fin]  = make_float2(e, s * e);
        sidx[fin] = tid;
    }
    if (tid == 0) {
        tse[NPRE]  = make_float2(INFINITY, INFINITY);
        tez[NPRE]  = make_float2(INFINITY, 0.0f);
        sidx[NPRE] = 0; sidx[NPRE + 1] = 0; sidx[NPRE + 2] = 0; sidx[NPRE + 3] = 0;
    }
    __syncthreads();

    // ================= sequential-chunk scan with block early-exit ================
    const int j0 = h * NJB;
    const int4* __restrict__ sidx4 = (const int4*)sidx;
    const int kbase = wid * KPW;                           // wave's k-slice in chunk

    // reduce-wave state (wave w<2 owns neuron n = 2*lane + w)
    float offA = 0.0f, offB = 0.0f;      // running prefix (per wave-partial)
    float preA = 0.0f, preB = 0.0f;      // prefix before firing 16-k group
    int   baseK = -1;                    // start of 16-k group containing firing
    bool  doneJ = false;

    // float2 gather: lane covers neurons (j0+2*lane, j0+2*lane+1) in one 8B load
#define LW2(idx) (*(const float2*)(Wt + (idx) * NPOST + j0 + 2 * lane))
#define LOADW2(kstart, dst)                                                   \
    {                                                                         \
        int4 Ia = sidx4[((kstart) >> 2) + 0];                                 \
        int4 Ib = sidx4[((kstart) >> 2) + 1];                                 \
        int4 Ic = sidx4[((kstart) >> 2) + 2];                                 \
        int4 Id = sidx4[((kstart) >> 2) + 3];                                 \
        dst[0]  = LW2(Ia.x); dst[1]  = LW2(Ia.y);                             \
        dst[2]  = LW2(Ia.z); dst[3]  = LW2(Ia.w);                             \
        dst[4]  = LW2(Ib.x); dst[5]  = LW2(Ib.y);                             \
        dst[6]  = LW2(Ib.z); dst[7]  = LW2(Ib.w);                             \
        dst[8]  = LW2(Ic.x); dst[9]  = LW2(Ic.y);                             \
        dst[10] = LW2(Ic.z); dst[11] = LW2(Ic.w);                             \
        dst[12] = LW2(Id.x); dst[13] = LW2(Id.y);                             \
        dst[14] = LW2(Id.z); dst[15] = LW2(Id.w);                             \
    }

    float2 wv[KPW];
    LOADW2(kbase, wv);

    for (int ch = 0; ch < NCHK; ++ch) {
        const int kk0 = ch * CLEN + kbase;
        // wave-local partials over its 16 k's (tez reads: wave-uniform broadcasts)
        float a0 = 0.0f, b0 = 0.0f, a1 = 0.0f, b1 = 0.0f;
#pragma unroll
        for (int i = 0; i < KPW; ++i) {
            float2 t = tez[kk0 + i];
            a0 = fmaf(wv[i].x, t.x, a0);
            b0 = fmaf(wv[i].x, t.y, b0);
            a1 = fmaf(wv[i].y, t.x, a1);
            b1 = fmaf(wv[i].y, t.y, b1);
        }
        pA[wid][2 * lane]     = a0; pB[wid][2 * lane]     = b0;
        pA[wid][2 * lane + 1] = a1; pB[wid][2 * lane + 1] = b1;
        __syncthreads();

        if (wid < 2) {
            const int n = 2 * lane + wid;
            // sub-gated prefix over the 16 wave-partials: gate every KPW k's.
            // Gate at boundary m: V(s_m) >= 1  <=>  crossing in some window k < m.
#pragma unroll
            for (int w = 0; w < NW; ++w) {
                float nA = offA + pA[w][n];
                float nB = offB + pB[w][n];
                if (!doneJ) {
                    float2 tn = tse[ch * CLEN + (w + 1) * KPW];   // last: pad ok
                    float gate = fmaf(nA, tn.x, -nB);
                    if (gate >= tn.y) {
                        baseK = ch * CLEN + w * KPW;
                        preA = offA; preB = offB;
                        doneJ = true;
                    }
                }
                offA = nA; offB = nB;
            }
            bool all = __all(doneJ);
            if (lane == 0) flags[wid] = all ? 1 : 0;
        }
        __syncthreads();
        if (flags[0] & flags[1]) break;        // uniform across block (typ. ch=0)
        // load next chunk only when continuing (rare): no wasted prefetch
        if (ch < NCHK - 1) LOADW2(kk0 + CLEN, wv);
    }

    // ================= resolve: waves 0-1, one neuron per lane =====================
    if (wid < 2) {
        const int n = 2 * lane + wid;
        const float* __restrict__ Wcol = Wt + j0 + n;
        float result = INFINITY;
        const float INV_E = 0.36787944117144233f;
        if (doneJ) {
            // fine delayed-gate rescan of the 16-k group [baseK, baseK+KPW)
            float wl[KPW];
#pragma unroll
            for (int i = 0; i < KPW; ++i) wl[i] = Wcol[sidx[baseK + i] * NPOST];
            float A = preA, Bq = preB;
            int fk = -1; float fA = 0.0f, fB = 0.0f;
#pragma unroll
            for (int i = 0; i < KPW; ++i) {
                const int k = baseK + i;
                float2 ez = tez[k];
                A  = fmaf(wl[i], ez.x, A);
                Bq = fmaf(wl[i], ez.y, Bq);
                if (fk < 0) {
                    // window k: V(s_{k+1}) >= 1, prefix inclusive of k
                    float2 tn = tse[k + 1];
                    float gate = fmaf(A, tn.x, -Bq);
                    if (gate >= tn.y) { fA = A; fB = Bq; fk = k; }
                }
            }

            if (fk >= 0) {
                float r   = fB / fA;
                float ezz = expf(fminf(fmaxf(r, -30.0f), 30.0f));
                float z   = -ezz / fA;
                bool valid = (fA > 0.0f) && (z >= -INV_E);
                float t = r - lambertw0_f(z);
                bool ok = valid && (t >= tse[fk].x) &&
                          (fk == NPRE - 1 || t <= tse[fk + 1].x);
                if (ok) {
                    result = t;
                } else {
                    // rare fp-edge fallback: faithful sequential scan from fk+1
                    float A2 = fA, B2 = fB;
                    for (int k = fk + 1; k < NPRE; ++k) {
                        float w = Wcol[sidx[k] * NPOST];
                        float2 ez2v = tez[k];
                        A2 = fmaf(w, ez2v.x, A2);
                        B2 = fmaf(w, ez2v.y, B2);
                        if (A2 <= 0.0f) continue;
                        float r2  = B2 / A2;
                        float ex2 = expf(fminf(fmaxf(r2, -30.0f), 30.0f));
                        float z2  = -ex2 / A2;
                        if (z2 < -INV_E) continue;
                        float t2 = r2 - lambertw0_f(z2);
                        if (t2 < tse[k].x) continue;
                        if (k < NPRE - 1 && t2 > tse[k + 1].x) continue;
                        result = t2;
                        break;
                    }
                }
            } else {
                // ultra-rare grouping/sequential mismatch: faithful full scan from 0
                float A2 = 0.0f, B2 = 0.0f;
                for (int k = 0; k < NPRE; ++k) {
                    float w = Wcol[sidx[k] * NPOST];
                    float2 ez2v = tez[k];
                    A2 = fmaf(w, ez2v.x, A2);
                    B2 = fmaf(w, ez2v.y, B2);
                    if (A2 <= 0.0f) continue;
                    float r2  = B2 / A2;
                    float ex2 = expf(fminf(fmaxf(r2, -30.0f), 30.0f));
                    float z2  = -ex2 / A2;
                    if (z2 < -INV_E) continue;
                    float t2 = r2 - lambertw0_f(z2);
                    if (t2 < tse[k].x) continue;
                    if (k < NPRE - 1 && t2 > tse[k + 1].x) continue;
                    result = t2;
                    break;
                }
            }
        }
        out[b * NPOST + j0 + n] = result;
    }
}

extern "C" void kernel_launch(void* const* d_in, const int* in_sizes, int n_in,
                              void* d_out, int out_size, void* d_ws, size_t ws_size,
                              hipStream_t stream) {
    const float* spikes  = (const float*)d_in[0];   // (128, 1024) f32
    const float* weights = (const float*)d_in[1];   // (1024, 256) f32
    float* outp = (float*)d_out;                    // (128, 256) f32
    ttfs_kernel<<<dim3(BATCH * 2), dim3(1024), 0, stream>>>(spikes, weights, outp);
}

// Round 16
// 12.804 us; speedup vs baseline: 1.1336x; 1.0509x over previous
//
#include <hip/hip_runtime.h>
#include <math.h>

#define BATCH 128
#define NPRE  1024
#define NPOST 256
#define NJB   128    // neurons per block (2 per lane)
#define NW    16     // waves per block
#define KPW   16     // k's per wave per chunk
#define CLEN  256    // chunk length = NW*KPW
#define NCHK  4      // NPRE / CLEN

__device__ __forceinline__ float lambertw0_f(float z) {
    // Principal branch for z in [-1/e, 0). Same clip+init as reference; Halley
    // converges cubically (worst init err ~0.21 -> 1e-3 -> 1e-9), so 5 iters is
    // fp32-converged; the reference's 12 are fixed-point no-ops beyond that.
    const float INV_E = 0.36787944117144233f;
    float zc = fminf(fmaxf(z, -INV_E + 1e-8f), -1e-30f);
    float w;
    if (zc < -0.2f) {
        w = -1.0f + sqrtf(2.0f * (1.0f + 2.718281828459045f * zc));
    } else {
        w = zc * (1.0f - zc);
    }
#pragma unroll
    for (int it = 0; it < 5; ++it) {
        float ew  = expf(w);
        float f   = w * ew - zc;
        float wp1 = w + 1.0f;
        w = w - f / (ew * wp1 - (w + 2.0f) * f / (2.0f * wp1));
    }
    return w;
}

__global__ __launch_bounds__(1024, 4)
void ttfs_kernel(const float* __restrict__ spikes,   // (BATCH, NPRE)
                 const float* __restrict__ Wt,       // (NPRE, NPOST)
                 float* __restrict__ out)            // (BATCH, NPOST)
{
    // ---- histogram-sort scratch ----
    __shared__ int    cnt[1024];
    __shared__ int    bstart[1025];
    __shared__ int    wsum[NW];
    __shared__ unsigned long long tmp64[NPRE];
    // ---- split tables ----
    __shared__ float2 tse[NPRE + 1];             // (s, e^s) sorted, +inf pad
    __shared__ float2 tez[NPRE + 1];             // (e^s, s*e^s) sorted
    __shared__ int    sidx[NPRE + 4];            // sorted original indices
    __shared__ float  pA[NW][NJB + 2], pB[NW][NJB + 2];
    __shared__ int    flags[2];

    const int tid  = threadIdx.x;
    const int lane = tid & 63;
    const int wid  = tid >> 6;
    const int b    = (int)blockIdx.x >> 1;
    const int h    = (int)blockIdx.x & 1;

    // ================= histogram rank-sort (stable by (key asc, idx asc)) ==========
    {
        float s = spikes[b * NPRE + tid];
        unsigned long long v =
            (((unsigned long long)__float_as_uint(s)) << 32) | (unsigned)tid;
        int bucket = (int)(s * 1024.0f);
        bucket = bucket < 0 ? 0 : (bucket > 1023 ? 1023 : bucket);

        cnt[tid] = 0;
        __syncthreads();
        int arr = atomicAdd(&cnt[bucket], 1);
        __syncthreads();

        int c0 = cnt[tid];
        int x  = c0;
#pragma unroll
        for (int d = 1; d < 64; d <<= 1) {
            int y = __shfl_up(x, d);
            if (lane >= d) x += y;
        }
        if (lane == 63) wsum[wid] = x;
        __syncthreads();
        // wave-wide shfl scan over the 16 wave totals (replaces serial LDS chain)
        int ws = (lane < NW) ? wsum[lane] : 0;
#pragma unroll
        for (int d = 1; d < NW; d <<= 1) {
            int y = __shfl_up(ws, d);
            if (lane >= d) ws += y;
        }
        int base = (wid == 0) ? 0 : __shfl(ws, wid - 1);
        bstart[tid] = base + x - c0;
        if (tid == 0) bstart[1024] = NPRE;
        __syncthreads();

        int slot = bstart[bucket] + arr;
        tmp64[slot] = v;
        __syncthreads();

        int st = bstart[bucket], en = bstart[bucket + 1];
        int rk = 0;
        for (int q = st; q < en; ++q) rk += (tmp64[q] < v);
        int fin = st + rk;

        float e = expf(s);
        tse[fin]  = make_float2(s, e);
        tez[fin]  = make_float2(e, s * e);
        sidx[fin] = tid;
    }
    if (tid == 0) {
        tse[NPRE]  = make_float2(INFINITY, INFINITY);
        tez[NPRE]  = make_float2(INFINITY, 0.0f);
        sidx[NPRE] = 0; sidx[NPRE + 1] = 0; sidx[NPRE + 2] = 0; sidx[NPRE + 3] = 0;
    }
    __syncthreads();

    // ================= sequential-chunk scan with block early-exit ================
    const int j0 = h * NJB;
    const float* __restrict__ Wc0 = Wt + j0 + lane;        // neuron = lane
    const float* __restrict__ Wc1 = Wt + j0 + 64 + lane;   // neuron = lane+64
    const int4* __restrict__ sidx4 = (const int4*)sidx;
    const int kbase = wid * KPW;                           // wave's k-slice in chunk

    // reduce-wave state (wave w<2 owns neuron n = w*64+lane)
    float offA = 0.0f, offB = 0.0f;      // running prefix (per wave-partial)
    float preA = 0.0f, preB = 0.0f;      // prefix before firing 16-k group
    int   baseK = -1;                    // start of 16-k group containing firing
    bool  doneJ = false;

#define LOADW2(kstart, dst)                                                   \
    {                                                                         \
        int4 Ia = sidx4[((kstart) >> 2) + 0];                                 \
        int4 Ib = sidx4[((kstart) >> 2) + 1];                                 \
        int4 Ic = sidx4[((kstart) >> 2) + 2];                                 \
        int4 Id = sidx4[((kstart) >> 2) + 3];                                 \
        dst[0]  = Wc0[Ia.x * NPOST]; dst[1]  = Wc0[Ia.y * NPOST];             \
        dst[2]  = Wc0[Ia.z * NPOST]; dst[3]  = Wc0[Ia.w * NPOST];             \
        dst[4]  = Wc0[Ib.x * NPOST]; dst[5]  = Wc0[Ib.y * NPOST];             \
        dst[6]  = Wc0[Ib.z * NPOST]; dst[7]  = Wc0[Ib.w * NPOST];             \
        dst[8]  = Wc0[Ic.x * NPOST]; dst[9]  = Wc0[Ic.y * NPOST];             \
        dst[10] = Wc0[Ic.z * NPOST]; dst[11] = Wc0[Ic.w * NPOST];             \
        dst[12] = Wc0[Id.x * NPOST]; dst[13] = Wc0[Id.y * NPOST];             \
        dst[14] = Wc0[Id.z * NPOST]; dst[15] = Wc0[Id.w * NPOST];             \
        dst[16] = Wc1[Ia.x * NPOST]; dst[17] = Wc1[Ia.y * NPOST];             \
        dst[18] = Wc1[Ia.z * NPOST]; dst[19] = Wc1[Ia.w * NPOST];             \
        dst[20] = Wc1[Ib.x * NPOST]; dst[21] = Wc1[Ib.y * NPOST];             \
        dst[22] = Wc1[Ib.z * NPOST]; dst[23] = Wc1[Ib.w * NPOST];             \
        dst[24] = Wc1[Ic.x * NPOST]; dst[25] = Wc1[Ic.y * NPOST];             \
        dst[26] = Wc1[Ic.z * NPOST]; dst[27] = Wc1[Ic.w * NPOST];             \
        dst[28] = Wc1[Id.x * NPOST]; dst[29] = Wc1[Id.y * NPOST];             \
        dst[30] = Wc1[Id.z * NPOST]; dst[31] = Wc1[Id.w * NPOST];             \
    }

    float wv[2 * KPW];
    LOADW2(kbase, wv);

    for (int ch = 0; ch < NCHK; ++ch) {
        const int kk0 = ch * CLEN + kbase;
        // wave-local partials over its 16 k's (tez reads: wave-uniform broadcasts)
        float a0 = 0.0f, b0 = 0.0f, a1 = 0.0f, b1 = 0.0f;
#pragma unroll
        for (int i = 0; i < KPW; ++i) {
            float2 t = tez[kk0 + i];
            a0 = fmaf(wv[i],       t.x, a0);
            b0 = fmaf(wv[i],       t.y, b0);
            a1 = fmaf(wv[KPW + i], t.x, a1);
            b1 = fmaf(wv[KPW + i], t.y, b1);
        }
        pA[wid][lane]      = a0; pB[wid][lane]      = b0;
        pA[wid][64 + lane] = a1; pB[wid][64 + lane] = b1;
        __syncthreads();

        if (wid < 2) {
            const int n = (wid << 6) + lane;
            // sub-gated prefix over the 16 wave-partials: gate every KPW k's.
            // Gate at boundary m: V(s_m) >= 1  <=>  crossing in some window k < m.
#pragma unroll
            for (int w = 0; w < NW; ++w) {
                float nA = offA + pA[w][n];
                float nB = offB + pB[w][n];
                if (!doneJ) {
                    float2 tn = tse[ch * CLEN + (w + 1) * KPW];   // last: pad ok
                    float gate = fmaf(nA, tn.x, -nB);
                    if (gate >= tn.y) {
                        baseK = ch * CLEN + w * KPW;
                        preA = offA; preB = offB;
                        doneJ = true;
                    }
                }
                offA = nA; offB = nB;
            }
            bool all = __all(doneJ);
            if (lane == 0) flags[wid] = all ? 1 : 0;
        }
        __syncthreads();
        if (flags[0] & flags[1]) break;        // uniform across block (typ. ch=0)
        // load next chunk only when continuing (rare): no wasted prefetch
        if (ch < NCHK - 1) LOADW2(kk0 + CLEN, wv);
    }

    // ================= resolve: waves 0-1, one neuron per lane =====================
    if (wid < 2) {
        const int n = (wid << 6) + lane;
        const float* __restrict__ Wcol = Wt + j0 + n;
        float result = INFINITY;
        const float INV_E = 0.36787944117144233f;
        if (doneJ) {
            // fine delayed-gate rescan of the 16-k group [baseK, baseK+KPW)
            // (baseK is 16-aligned: batch sidx reads as int4)
            float wl[KPW];
#pragma unroll
            for (int q = 0; q < KPW / 4; ++q) {
                int4 I = sidx4[(baseK >> 2) + q];
                wl[4 * q + 0] = Wcol[I.x * NPOST];
                wl[4 * q + 1] = Wcol[I.y * NPOST];
                wl[4 * q + 2] = Wcol[I.z * NPOST];
                wl[4 * q + 3] = Wcol[I.w * NPOST];
            }
            float A = preA, Bq = preB;
            int fk = -1; float fA = 0.0f, fB = 0.0f;
#pragma unroll
            for (int i = 0; i < KPW; ++i) {
                const int k = baseK + i;
                float2 ez = tez[k];
                A  = fmaf(wl[i], ez.x, A);
                Bq = fmaf(wl[i], ez.y, Bq);
                if (fk < 0) {
                    // window k: V(s_{k+1}) >= 1, prefix inclusive of k
                    float2 tn = tse[k + 1];
                    float gate = fmaf(A, tn.x, -Bq);
                    if (gate >= tn.y) { fA = A; fB = Bq; fk = k; }
                }
            }

            if (fk >= 0) {
                float r   = fB / fA;
                float ezz = expf(fminf(fmaxf(r, -30.0f), 30.0f));
                float z   = -ezz / fA;
                bool valid = (fA > 0.0f) && (z >= -INV_E);
                float t = r - lambertw0_f(z);
                bool ok = valid && (t >= tse[fk].x) &&
                          (fk == NPRE - 1 || t <= tse[fk + 1].x);
                if (ok) {
                    result = t;
                } else {
                    // rare fp-edge fallback: faithful sequential scan from fk+1
                    float A2 = fA, B2 = fB;
                    for (int k = fk + 1; k < NPRE; ++k) {
                        float w = Wcol[sidx[k] * NPOST];
                        float2 ez2v = tez[k];
                        A2 = fmaf(w, ez2v.x, A2);
                        B2 = fmaf(w, ez2v.y, B2);
                        if (A2 <= 0.0f) continue;
                        float r2  = B2 / A2;
                        float ex2 = expf(fminf(fmaxf(r2, -30.0f), 30.0f));
                        float z2  = -ex2 / A2;
                        if (z2 < -INV_E) continue;
                        float t2 = r2 - lambertw0_f(z2);
                        if (t2 < tse[k].x) continue;
                        if (k < NPRE - 1 && t2 > tse[k + 1].x) continue;
                        result = t2;
                        break;
                    }
                }
            } else {
                // ultra-rare grouping/sequential mismatch: faithful full scan from 0
                float A2 = 0.0f, B2 = 0.0f;
                for (int k = 0; k < NPRE; ++k) {
                    float w = Wcol[sidx[k] * NPOST];
                    float2 ez2v = tez[k];
                    A2 = fmaf(w, ez2v.x, A2);
                    B2 = fmaf(w, ez2v.y, B2);
                    if (A2 <= 0.0f) continue;
                    float r2  = B2 / A2;
                    float ex2 = expf(fminf(fmaxf(r2, -30.0f), 30.0f));
                    float z2  = -ex2 / A2;
                    if (z2 < -INV_E) continue;
                    float t2 = r2 - lambertw0_f(z2);
                    if (t2 < tse[k].x) continue;
                    if (k < NPRE - 1 && t2 > tse[k + 1].x) continue;
                    result = t2;
                    break;
                }
            }
        }
        out[b * NPOST + j0 + n] = result;
    }
}

extern "C" void kernel_launch(void* const* d_in, const int* in_sizes, int n_in,
                              void* d_out, int out_size, void* d_ws, size_t ws_size,
                              hipStream_t stream) {
    const float* spikes  = (const float*)d_in[0];   // (128, 1024) f32
    const float* weights = (const float*)d_in[1];   // (1024, 256) f32
    float* outp = (float*)d_out;                    // (128, 256) f32
    ttfs_kernel<<<dim3(BATCH * 2), dim3(1024), 0, stream>>>(spikes, weights, outp);
}